// Round 5
// baseline (480.040 us; speedup 1.0000x reference)
//
#include <hip/hip_runtime.h>

// Boosted neural LDPC min-sum decoder, MI355X — fused per-iteration kernel,
// z-fastest layout, check-state recompute (no pass-B kernel).
// Sizes fixed by setup_inputs(): B=32, Z=384, N=68, M=46, dc=7, E=322, iters=8.
#define B_   32
#define Z_   384
#define N_   68
#define M_   46
#define DC_  7
#define E_   (M_ * DC_)      // 322
#define ZN   (Z_ * N_)       // 26112
#define ZM   (Z_ * M_)       // 17664
#define INIT_STATE ((16u << 10) | (16u << 15))   // q1=0, q2=0 -> all c2v decode to 0

// ---- workspace layout (int32 offsets), all big arrays z-fastest ----
#define XAT_OFF   0                          // float xat[B*ZN]
#define LT0_OFF   (B_ * ZN)                  // float lt ping
#define LT1_OFF   (LT0_OFF + B_ * ZN)        // float lt pong
#define ST0_OFF   (LT1_OFF + B_ * ZN)        // int   state ping [B*ZM]
#define ST1_OFF   (ST0_OFF + B_ * ZM)        // int   state pong [B*ZM]
#define EVS_OFF   (ST1_OFF + B_ * ZM)        // int   evs[E]     vn | s<<7   (check-major)
#define OFFS_OFF  (EVS_OFF + E_)             // int   offs[N+1]  CSR per variable
#define LST_OFF   (OFFS_OFF + N_ + 1)        // int   lists[E]   s | m<<9 | j<<15
#define WS_INTS   (LST_OFF + E_)             // ~3.64M ints ≈ 14.6 MB

// state word layout (20 bits):
//  [0:6] neg bits | [7:9] first-min edge | [10:14] q1*2+16 | [15:19] q2*2+16
__device__ __forceinline__ int decode2(unsigned st, int j) {
    int neg   = (st >> j) & 1;
    int q1    = (int)((st >> 10) & 31) - 16;
    int q2    = (int)((st >> 15) & 31) - 16;
    int first = (int)((st >> 7) & 7);
    int q     = (j == first) ? q2 : q1;
    int par   = (__popc(st & 127u) - neg) & 1;   // parity of other edges' signs
    return par ? -q : q;                          // message * 2 (exact int)
}

// ==================== table-build kernel (1 block, once per launch) ====================
__global__ __launch_bounds__(1024)
void k_tables(const int* __restrict__ vn_idx, const int* __restrict__ shifts,
              int* __restrict__ ws)
{
    __shared__ int evs[E_];
    __shared__ int offs[N_ + 1];
    __shared__ int lists[E_];
    const int tid = threadIdx.x;
    if (tid < E_) evs[tid] = vn_idx[tid] | (shifts[tid] << 7);
    __syncthreads();
    if (tid < N_) {
        int c = 0;
        for (int e = 0; e < E_; ++e) c += ((evs[e] & 127) == tid);
        offs[tid + 1] = c;
    }
    if (tid == 0) offs[0] = 0;
    __syncthreads();
    if (tid == 0) { for (int n = 0; n < N_; ++n) offs[n + 1] += offs[n]; }
    __syncthreads();
    if (tid < N_) {
        int p = offs[tid];
        for (int e = 0; e < E_; ++e) {
            int rec = evs[e];
            if ((rec & 127) == tid) {
                int s = rec >> 7;
                lists[p++] = s | ((e / DC_) << 9) | ((e % DC_) << 15);
            }
        }
    }
    __syncthreads();
    if (tid < E_) { ws[EVS_OFF + tid] = evs[tid]; ws[LST_OFF + tid] = lists[tid]; }
    if (tid < N_ + 1) ws[OFFS_OFF + tid] = offs[tid];
}

// ==================== pre-transpose: xat[b][n][z] = xa[b][z][n] ====================
__global__ __launch_bounds__(256)
void k_pre(const float* __restrict__ xa, float* __restrict__ xat)
{
    __shared__ float tile[N_ * 65];           // [n][zl], pad 65 to break conflicts
    const int b  = blockIdx.x / 6;
    const int t  = blockIdx.x - b * 6;
    const int z0 = t * 64;
    const int tid = threadIdx.x;
    const float* src = xa + (size_t)b * ZN + (size_t)z0 * N_;
    for (int i = tid; i < 64 * N_; i += 256) {  // contiguous 17 KB read
        int r = i / N_, n = i - r * N_;
        tile[n * 65 + r] = src[i];
    }
    __syncthreads();
    float* dst = xat + (size_t)b * ZN + z0;
    for (int i = tid; i < 64 * N_; i += 256) {
        int n = i >> 6, zl = i & 63;
        dst[n * Z_ + zl] = tile[n * 65 + zl];
    }
}

// ==================== fused iteration kernel ====================
// block = (b, n), thread = z. For each of variable n's dv edges (m,s,j):
// recompute check m's new state at row zc=z-s from lt_old (7 coalesced gathers)
// + the check's OWN old state word; accumulate decode; j==0 edge writes st_new.
// Then lt_new[n][z] = fl(xat + 0.5*tot). All loads coalesced & independent.
__global__ __launch_bounds__(384)
void k_fused(const float* __restrict__ xat, const float* __restrict__ cw,
             const int* __restrict__ ws_tbl,
             const int* __restrict__ st_old, int* __restrict__ st_new,
             const float* __restrict__ lt_old_g, float* __restrict__ lt_new_g,
             int it, int use_init)
{
    __shared__ int evs[E_];
    __shared__ int vlist[E_];
    __shared__ int s_cnt;
    const int tid = threadIdx.x;
    const int b = blockIdx.x / N_;
    const int n = blockIdx.x - b * N_;
    if (tid < E_) evs[tid] = ws_tbl[EVS_OFF + tid];
    if (tid == 0) s_cnt = ws_tbl[OFFS_OFF + n + 1] - ws_tbl[OFFS_OFF + n];
    {
        int o = ws_tbl[OFFS_OFF + n];
        int e = ws_tbl[OFFS_OFF + n + 1];
        for (int k = o + tid; k < e; k += 384) vlist[k - o] = ws_tbl[LST_OFF + k];
    }
    __syncthreads();

    const int z = tid;
    const float* lt_old = lt_old_g + (size_t)b * ZN;
    const int*   stob   = st_old + (size_t)b * ZM;
    int*         stnb   = st_new + (size_t)b * ZM;
    const float  w      = cw[it];
    const int    cnt    = s_cnt;

    int t2 = 0;
    for (int k = 0; k < cnt; ++k) {            // wave-uniform trip count
        int rec = vlist[k];
        int s = rec & 511;
        int m = (rec >> 9) & 63;
        int j = (rec >> 15) & 7;
        int zc = z - s; if (zc < 0) zc += Z_;  // check-frame row
        unsigned sto = use_init ? INIT_STATE : (unsigned)stob[m * Z_ + zc];

        // ---- recompute check m @ row zc (bitwise-identical in every block) ----
        float m1 = 1e30f, m2 = 1e30f;
        int f = 0, negb = 0;
        #pragma unroll
        for (int j2 = 0; j2 < DC_; ++j2) {
            int rec2 = evs[m * DC_ + j2];
            int vn2 = rec2 & 127;
            int s2  = rec2 >> 7;
            int zr = zc + s2; if (zr >= Z_) zr -= Z_;
            int c2 = decode2(sto, j2);
            // identical operand order to JAX: fl(fl(llr + tot) - c2v), then clip
            float v = lt_old[vn2 * Z_ + zr] - 0.5f * (float)c2;
            v = fminf(fmaxf(v, -20.0f), 20.0f);
            negb |= (v < 0.0f) << j2;
            float a = fabsf(v);
            if (a < m1) { m2 = m1; m1 = a; f = j2; }
            else if (a < m2) { m2 = a; }
        }
        // quantize-STE forward: clip(rint(2*w*min)/2, +-7.5), stored as int*2
        float r1 = fminf(fmaxf(rintf(w * m1 * 2.0f), -15.0f), 15.0f);
        float r2 = fminf(fmaxf(rintf(w * m2 * 2.0f), -15.0f), 15.0f);
        unsigned stw = (unsigned)(negb | (f << 7) | (((int)r1 + 16) << 10)
                                       | (((int)r2 + 16) << 15));
        if (j == 0) stnb[m * Z_ + zc] = (int)stw;  // exactly one writer per check
        t2 += decode2(stw, j);
    }
    // fl(llr + tot): tot exact int in half-steps
    lt_new_g[(size_t)b * ZN + n * Z_ + z] =
        xat[(size_t)b * ZN + n * Z_ + z] + 0.5f * (float)t2;
}

// ==================== fallback: single-block-per-batch kernel (small ws) ====================
__global__ __launch_bounds__(1024)
void ldpc_decode_kernel(const float* __restrict__ xa,
                        const float* __restrict__ cw,
                        const int*   __restrict__ vn_idx,
                        const int*   __restrict__ shifts,
                        float* out, int iters)
{
    __shared__ short tot[ZN];
    __shared__ int   evs[E_];
    __shared__ int   offs[N_ + 1];
    __shared__ int   lists[E_];
    __shared__ float wlds[8];

    const int tid = threadIdx.x;
    const int b   = blockIdx.x;
    const float* xab = xa + (size_t)b * ZN;
    float* outb = out + (size_t)b * ZN;
    int* stateg = (int*)outb;

    if (tid < E_) evs[tid] = vn_idx[tid] | (shifts[tid] << 7);
    if (tid < iters && tid < 8) wlds[tid] = cw[tid];
    __syncthreads();
    if (tid < N_) {
        int c = 0;
        for (int e = 0; e < E_; ++e) c += ((evs[e] & 127) == tid);
        offs[tid + 1] = c;
    }
    if (tid == 0) offs[0] = 0;
    __syncthreads();
    if (tid == 0) { for (int n = 0; n < N_; ++n) offs[n + 1] += offs[n]; }
    __syncthreads();
    if (tid < N_) {
        int p = offs[tid];
        for (int e = 0; e < E_; ++e) {
            int rec = evs[e];
            if ((rec & 127) == tid) {
                int s = rec >> 7;
                lists[p++] = s | ((e / DC_) << 9) | ((e % DC_) << 15);
            }
        }
    }
    __syncthreads();

    for (int i = tid; i < ZM; i += 1024) stateg[i] = (int)INIT_STATE;
    __syncthreads();

    for (int it = 0; it < iters; ++it) {
        for (int i = tid; i < ZN; i += 1024) {
            int z = i / N_, n = i - z * N_, t2 = 0;
            int kend = offs[n + 1];
            for (int k = offs[n]; k < kend; ++k) {
                int rec = lists[k];
                int s = rec & 511, m = (rec >> 9) & 63, j = rec >> 15;
                int zs = z - s; if (zs < 0) zs += Z_;
                t2 += decode2((unsigned)stateg[zs * M_ + m], j);
            }
            tot[i] = (short)t2;
        }
        __syncthreads();
        const float w = wlds[it];
        for (int i = tid; i < ZM; i += 1024) {
            int z = i / M_, m = i - z * M_;
            unsigned st = (unsigned)stateg[i];
            float m1 = 1e30f, m2 = 1e30f;
            int f = 0, negb = 0;
            #pragma unroll
            for (int j = 0; j < DC_; ++j) {
                int rec = evs[m * DC_ + j];
                int vn = rec & 127, s = rec >> 7;
                int zr = z + s; if (zr >= Z_) zr -= Z_;
                int c2 = decode2(st, j);
                int idx = zr * N_ + vn;
                float v = (xab[idx] + 0.5f * (float)tot[idx]) - 0.5f * (float)c2;
                v = fminf(fmaxf(v, -20.0f), 20.0f);
                negb |= (v < 0.0f) << j;
                float a = fabsf(v);
                if (a < m1) { m2 = m1; m1 = a; f = j; }
                else if (a < m2) { m2 = a; }
            }
            float r1 = fminf(fmaxf(rintf(w * m1 * 2.0f), -15.0f), 15.0f);
            float r2 = fminf(fmaxf(rintf(w * m2 * 2.0f), -15.0f), 15.0f);
            stateg[i] = (int)(unsigned)(negb | (f << 7) | (((int)r1 + 16) << 10) | (((int)r2 + 16) << 15));
        }
        __syncthreads();
    }

    for (int i = tid; i < ZN; i += 1024) {
        int z = i / N_, n = i - z * N_, t2 = 0;
        int kend = offs[n + 1];
        for (int k = offs[n]; k < kend; ++k) {
            int rec = lists[k];
            int s = rec & 511, m = (rec >> 9) & 63, j = rec >> 15;
            int zs = z - s; if (zs < 0) zs += Z_;
            t2 += decode2((unsigned)stateg[zs * M_ + m], j);
        }
        tot[i] = (short)t2;
    }
    __syncthreads();
    for (int i = tid; i < ZN; i += 1024) {
        int n = i / Z_, z = i - n * Z_;
        outb[i] = xab[z * N_ + n] + 0.5f * (float)tot[z * N_ + n];
    }
}

extern "C" void kernel_launch(void* const* d_in, const int* in_sizes, int n_in,
                              void* d_out, int out_size, void* d_ws, size_t ws_size,
                              hipStream_t stream) {
    const float* xa = (const float*)d_in[0];
    const float* cw = (const float*)d_in[1];
    const int* vn   = (const int*)d_in[2];
    // d_in[3] = cn_idx: repeat(arange(M), dc) by construction — implicit.
    const int* sh   = (const int*)d_in[4];
    int iters = in_sizes[1];
    float* outp = (float*)d_out;

    if (ws_size >= (size_t)WS_INTS * sizeof(int)) {
        int*   ws  = (int*)d_ws;
        float* xat = (float*)d_ws + XAT_OFF;
        float* ltb[2] = { (float*)d_ws + LT0_OFF, (float*)d_ws + LT1_OFF };
        int*   stb[2] = { ws + ST0_OFF, ws + ST1_OFF };

        if (iters == 0) {   // out = transpose(xa)
            hipLaunchKernelGGL(k_pre, dim3(B_ * 6), dim3(256), 0, stream, xa, outp);
            return;
        }
        hipLaunchKernelGGL(k_tables, dim3(1), dim3(1024), 0, stream, vn, sh, ws);
        hipLaunchKernelGGL(k_pre, dim3(B_ * 6), dim3(256), 0, stream, xa, xat);
        for (int it = 0; it < iters; ++it) {
            const float* src = (it == 0) ? xat : ltb[(it - 1) & 1];
            float*       dst = (it == iters - 1) ? outp : ltb[it & 1];
            hipLaunchKernelGGL(k_fused, dim3(B_ * N_), dim3(Z_), 0, stream,
                               xat, cw, ws, stb[(it + 1) & 1], stb[it & 1],
                               src, dst, it, (it == 0) ? 1 : 0);
        }
    } else {
        hipLaunchKernelGGL(ldpc_decode_kernel, dim3(B_), dim3(1024), 0, stream,
                           xa, cw, vn, sh, outp, iters);
    }
}